// Round 14
// baseline (94.670 us; speedup 1.0000x reference)
//
#include <hip/hip_runtime.h>
#include <hip/hip_fp16.h>
#include <stdint.h>

#define NN 8192          // nodes
#define HID 256          // hidden
#define NH 4             // heads
#define HD 64            // head dim
#define NE 262144        // edges
#define WPR (NN / 32)    // bitmap words per row = 256
#define CAP 128          // max neighbors per row (Binomial(262k,1/8192): max ~57)
#define NQKV 768         // fused QKV output width
#define G1B 384          // gemm1 blocks (128x128 tiles) inside fused kernel

typedef __attribute__((ext_vector_type(8))) short s16x8;      // 8 halves (4 VGPRs)
typedef __attribute__((ext_vector_type(4))) float f32x4;      // MFMA C/D frag
typedef _Float16 f16x2 __attribute__((ext_vector_type(2)));   // v_dot2 operand

__device__ __forceinline__ float fdot2(f16x2 a, f16x2 b, float c) {
#if __has_builtin(__builtin_amdgcn_fdot2)
    return __builtin_amdgcn_fdot2(a, b, c, false);
#else
    return c + (float)a.x * (float)b.x + (float)a.y * (float)b.y;
#endif
}

__device__ __forceinline__ void gload_lds16(const unsigned short* g, unsigned short* l) {
    __builtin_amdgcn_global_load_lds(
        (const __attribute__((address_space(1))) unsigned int*)g,
        (__attribute__((address_space(3))) unsigned int*)l, 16, 0, 0);
}

// ---------------------------------------------------------------------------
// Zero the bitmap: 2048 blocks x 256 thr x 16B = 8 MB
// ---------------------------------------------------------------------------
__global__ __launch_bounds__(256) void zero_kernel(uint4* __restrict__ p)
{
    p[blockIdx.x * 256 + threadIdx.x] = make_uint4(0, 0, 0, 0);
}

// ---------------------------------------------------------------------------
// Fused prep: [0,1024) edge scatter | [1024,3072) X->fp16 (4/thr)
//             [3072,4096) W^T->fp16 + qkv bias
// ---------------------------------------------------------------------------
__global__ __launch_bounds__(256) void prep_kernel(
    const float* __restrict__ X,
    const float* __restrict__ Wq, const float* __restrict__ Wk,
    const float* __restrict__ Wv, const float* __restrict__ Wo,
    const float* __restrict__ bq, const float* __restrict__ bk,
    const float* __restrict__ bv, const int* __restrict__ ei,
    uint32_t* __restrict__ bitmap, unsigned short* __restrict__ Xh,
    unsigned short* __restrict__ W2Tq, unsigned short* __restrict__ W2To,
    float* __restrict__ biasq)
{
    const int b = blockIdx.x, tid = threadIdx.x;
    if (b < 1024) {                                   // ---- edge scatter ----
        int e = b * 256 + tid;
        int r = ei[e];
        int c = ei[NE + e];
        atomicOr(&bitmap[(size_t)r * WPR + (c >> 5)], 1u << (c & 31));
    } else if (b < 3072) {                            // ---- X -> fp16 ----
        int i4 = ((b - 1024) * 256 + tid) * 4;        // covers NN*HID exactly
        float4 x = *(const float4*)(X + i4);
        __half2 h0 = __floats2half2_rn(x.x, x.y);
        __half2 h1 = __floats2half2_rn(x.z, x.w);
        uint2 w;
        w.x = *(unsigned*)&h0;
        w.y = *(unsigned*)&h1;
        *(uint2*)(Xh + i4) = w;
    } else {                                          // ---- W^T -> fp16 ----
        int lin = (b - 3072) * 256 + tid;             // 262144 = 1024*256
        int n = lin >> 8, k = lin & 255;
        const float* W; int ns; unsigned short* dst;
        if (n < NQKV) {
            W  = (n < 256) ? Wq : (n < 512) ? Wk : Wv;
            ns = n & 255;
            dst = W2Tq + (size_t)n * HID + k;
            if (k == 0) {
                const float* bsrc = (n < 256) ? bq : (n < 512) ? bk : bv;
                biasq[n] = bsrc[ns];
            }
        } else {
            W = Wo; ns = n - NQKV;
            dst = W2To + (size_t)ns * HID + k;
        }
        __half h = __float2half(W[(size_t)k * HID + ns]);
        *dst = *(unsigned short*)&h;
    }
}

// ---------------------------------------------------------------------------
// fp16 MFMA GEMM tile body (BM=128, BN template): C = A*B^T + bias, fp32 acc.
// 4 waves 2x2, each 64 x BN/2 (4 x BN/32 frags of 16x16x32 f16). K=256.
// ---------------------------------------------------------------------------
template<int BN, bool HALF_OUT>
__device__ __forceinline__ void gemm_body(
    const unsigned short* __restrict__ A, const unsigned short* __restrict__ BT,
    const float* __restrict__ bias, void* __restrict__ Cv, int N,
    int m0, int n0, unsigned short* Alds, unsigned short* Blds)
{
    constexpr int NFR = BN / 32;                    // N-frags per wave
    const int tid  = threadIdx.x;
    const int lane = tid & 63, wave = tid >> 6;
    const int wm = wave >> 1, wn = wave & 1;

    const int r0 = tid >> 2, cc0 = tid & 3;
    const int r1 = (tid + 256) >> 2, cc1 = (tid + 256) & 3;

    f32x4 acc[4][NFR];
    #pragma unroll
    for (int i = 0; i < 4; ++i)
        #pragma unroll
        for (int j = 0; j < NFR; ++j)
            acc[i][j] = (f32x4){0.f, 0.f, 0.f, 0.f};

    for (int step = 0; step < 8; ++step) {
        const int kk = step * 32;
        __syncthreads();
        gload_lds16(A + (size_t)(m0 + r0) * HID + kk + cc0 * 8, &Alds[tid * 8]);
        gload_lds16(A + (size_t)(m0 + r1) * HID + kk + cc1 * 8, &Alds[(tid + 256) * 8]);
        gload_lds16(BT + (size_t)(n0 + r0) * HID + kk + cc0 * 8, &Blds[tid * 8]);
        if constexpr (BN == 128)
            gload_lds16(BT + (size_t)(n0 + r1) * HID + kk + cc1 * 8, &Blds[(tid + 256) * 8]);
        __syncthreads();

        s16x8 af[4], bfr[NFR];
        #pragma unroll
        for (int i = 0; i < 4; ++i)
            af[i] = *(const s16x8*)&Alds[(wm * 64 + i * 16 + (lane & 15)) * 32 + (lane >> 4) * 8];
        #pragma unroll
        for (int j = 0; j < NFR; ++j)
            bfr[j] = *(const s16x8*)&Blds[(wn * (BN / 2) + j * 16 + (lane & 15)) * 32 + (lane >> 4) * 8];
        #pragma unroll
        for (int i = 0; i < 4; ++i)
            #pragma unroll
            for (int j = 0; j < NFR; ++j)
                acc[i][j] = __builtin_amdgcn_mfma_f32_16x16x32_f16(af[i], bfr[j], acc[i][j], 0, 0, 0);
    }

    // epilogue: C/D layout col=lane&15, row=(lane>>4)*4+reg
    #pragma unroll
    for (int i = 0; i < 4; ++i) {
        #pragma unroll
        for (int j = 0; j < NFR; ++j) {
            int gcol = n0 + wn * (BN / 2) + j * 16 + (lane & 15);
            float bb = bias[gcol];
            #pragma unroll
            for (int r = 0; r < 4; ++r) {
                int grow = m0 + wm * 64 + i * 16 + (lane >> 4) * 4 + r;
                float v = acc[i][j][r] + bb;
                if constexpr (HALF_OUT)
                    ((__half*)Cv)[(size_t)grow * N + gcol] = __float2half(v);
                else
                    ((float*)Cv)[(size_t)grow * N + gcol] = v;
            }
        }
    }
}

// ---------------------------------------------------------------------------
// Fused dispatch: [0, G1B) QKV GEMM (128x128 tiles, XCD swizzle) |
//                 [G1B, G1B+2048) bitmap -> capped neighbor lists (wave/row)
// ---------------------------------------------------------------------------
__global__ __launch_bounds__(256) void gemm_csr_kernel(
    const unsigned short* __restrict__ Xh, const unsigned short* __restrict__ W2Tq,
    const float* __restrict__ biasq, __half* __restrict__ QKV,
    const uint32_t* __restrict__ bitmap, int* __restrict__ nbr, int* __restrict__ cnt)
{
    __shared__ __align__(16) unsigned short Alds[128 * 32];
    __shared__ __align__(16) unsigned short Blds[128 * 32];

    if (blockIdx.x < G1B) {
        constexpr int q8 = G1B >> 3;
        const int orig = blockIdx.x;
        const int id = (orig & 7) * q8 + (orig >> 3);       // XCD-contiguous
        gemm_body<128, true>(Xh, W2Tq, biasq, QKV, NQKV,
                             (id & 63) * 128, (id >> 6) * 128, Alds, Blds);
        return;
    }
    // ---- build_csr: one wave per row ----
    const int row = (blockIdx.x - G1B) * 4 + (threadIdx.x >> 6);
    const int lane = threadIdx.x & 63;
    const uint32_t* rp = bitmap + (size_t)row * WPR + lane * 4;
    uint32_t w0 = rp[0], w1 = rp[1], w2 = rp[2], w3 = rp[3];
    int pc = __popc(w0) + __popc(w1) + __popc(w2) + __popc(w3);
    int scan = pc;
    #pragma unroll
    for (int off = 1; off < 64; off <<= 1) {
        int t = __shfl_up(scan, off);
        if (lane >= off) scan += t;
    }
    int idx = scan - pc;
    int* dst = nbr + (size_t)row * CAP;
    const int base = lane * 128;
    uint32_t ws4[4] = {w0, w1, w2, w3};
    #pragma unroll
    for (int i = 0; i < 4; ++i) {
        uint32_t w = ws4[i];
        int cb = base + i * 32;
        while (w) {
            int b = __ffs(w) - 1;
            if (idx < CAP) dst[idx] = cb + b;
            ++idx;
            w &= w - 1;
        }
    }
    if (lane == 63) cnt[row] = min(scan, CAP);
}

// ---------------------------------------------------------------------------
// Standalone GEMM (out-projection): BM=128, BN=64; 256 blocks, XCD swizzle.
// ---------------------------------------------------------------------------
template<int BN, bool HALF_OUT>
__global__ __launch_bounds__(256) void gemm_kernel(
    const unsigned short* __restrict__ A, const unsigned short* __restrict__ BT,
    const float* __restrict__ bias, void* __restrict__ Cv, int N)
{
    __shared__ __align__(16) unsigned short Alds[128 * 32];
    __shared__ __align__(16) unsigned short Blds[BN * 32];
    const int nwg = gridDim.x, orig = blockIdx.x, q8 = nwg >> 3;
    const int id = (orig & 7) * q8 + (orig >> 3);
    gemm_body<BN, HALF_OUT>(A, BT, bias, Cv, N,
                            (id & 63) * 128, (id >> 6) * BN, Alds, Blds);
}

// ---------------------------------------------------------------------------
// Sparse attention, WAVE-PER-ROW, zero LDS/barriers; ONE dwordx4 gather per
// edge (K|V contiguous 1KB in the QKV row). Lane l<32 holds K[8l..8l+7]
// (head l>>3); lane l>=32 holds V[8(l-32)..+8]. Score: 4 fdot2 on K-lanes,
// xor-reduce over offs {1,2,4,32} with V-lane partials zeroed (score lands
// in both halves of the head group). PV: V-lanes accumulate 8 cols each.
// ---------------------------------------------------------------------------
__global__ __launch_bounds__(256, 8) void attn_kernel(
    const __half* __restrict__ QKV, const int* __restrict__ nbr,
    const int* __restrict__ cntg, __half* __restrict__ ctx)
{
    const int row  = blockIdx.x * 4 + (threadIdx.x >> 6);
    const int lane = threadIdx.x & 63;
    const bool isK = lane < 32;
    const int cnt  = cntg[row];

    // Q slice matching this lane's K columns: halves 8*(lane&31)..+8
    uint4 qraw = ((const uint4*)(QKV + (size_t)row * NQKV))[lane & 31];
    union { uint4 u4; f16x2 h[4]; } uq; uq.u4 = qraw;

    float m = -INFINITY, l = 0.f;
    float a0 = 0.f, a1 = 0.f, a2 = 0.f, a3 = 0.f;
    float a4 = 0.f, a5 = 0.f, a6 = 0.f, a7 = 0.f;

    for (int j0 = 0; j0 < cnt; j0 += 64) {
        int mynb = (j0 + lane < cnt) ? nbr[(size_t)row * CAP + j0 + lane] : 0;
        const int nb = min(64, cnt - j0);
        for (int b = 0; b < nb; b += 8) {
            int idx[8];
            #pragma unroll
            for (int u = 0; u < 8; ++u) idx[u] = __shfl(mynb, b + u);
            uint4 kvv[8];
            #pragma unroll
            for (int u = 0; u < 8; ++u)            // 8 x dwordx4 in flight
                kvv[u] = ((const uint4*)(QKV + (size_t)idx[u] * NQKV + 256))[lane];
            float s[8];
            #pragma unroll
            for (int u = 0; u < 8; ++u) {
                union { uint4 u4; f16x2 h[4]; } uk; uk.u4 = kvv[u];
                float p = fdot2(uq.h[0], uk.h[0], 0.f);
                p = fdot2(uq.h[1], uk.h[1], p);
                p = fdot2(uq.h[2], uk.h[2], p);
                p = fdot2(uq.h[3], uk.h[3], p);
                p = isK ? p : 0.f;                 // V-lanes contribute 0
                #pragma unroll
                for (int off = 1; off < 8; off <<= 1) p += __shfl_xor(p, off);
                p += __shfl_xor(p, 32);            // join K- and V-halves
                s[u] = (b + u < nb) ? p * 0.125f : -INFINITY;
            }
            float bm = s[0];
            #pragma unroll
            for (int u = 1; u < 8; ++u) bm = fmaxf(bm, s[u]);
            float mn = fmaxf(m, bm);               // finite (>=1 valid score)
            float sc = expf(m - mn);               // first batch: exp(-inf)=0
            a0 *= sc; a1 *= sc; a2 *= sc; a3 *= sc;
            a4 *= sc; a5 *= sc; a6 *= sc; a7 *= sc;
            l *= sc;
            #pragma unroll
            for (int u = 0; u < 8; ++u) {
                float w = expf(s[u] - mn);         // masked: exp(-inf)=0
                l += w;
                union { uint4 u4; __half2 h[4]; } uv; uv.u4 = kvv[u];
                float2 f0 = __half22float2(uv.h[0]);
                float2 f1 = __half22float2(uv.h[1]);
                float2 f2 = __half22float2(uv.h[2]);
                float2 f3 = __half22float2(uv.h[3]);
                a0 = fmaf(w, f0.x, a0); a1 = fmaf(w, f0.y, a1);
                a2 = fmaf(w, f1.x, a2); a3 = fmaf(w, f1.y, a3);
                a4 = fmaf(w, f2.x, a4); a5 = fmaf(w, f2.y, a5);
                a6 = fmaf(w, f3.x, a6); a7 = fmaf(w, f3.y, a7);
            }
            m = mn;
        }
    }

    // V-lanes hold ctx cols 8*(lane-32)..+8; K-lanes' acc is unused garbage.
    if (!isK) {
        uint4 outw = make_uint4(0u, 0u, 0u, 0u);   // cnt==0 -> zeros
        if (cnt > 0) {
            float rl = 1.f / l;
            __half2 o0 = __floats2half2_rn(a0 * rl, a1 * rl);
            __half2 o1 = __floats2half2_rn(a2 * rl, a3 * rl);
            __half2 o2 = __floats2half2_rn(a4 * rl, a5 * rl);
            __half2 o3 = __floats2half2_rn(a6 * rl, a7 * rl);
            outw.x = *(unsigned*)&o0;
            outw.y = *(unsigned*)&o1;
            outw.z = *(unsigned*)&o2;
            outw.w = *(unsigned*)&o3;
        }
        ((uint4*)(ctx + (size_t)row * HID))[lane - 32] = outw;
    }
}

// ---------------------------------------------------------------------------
extern "C" void kernel_launch(void* const* d_in, const int* in_sizes, int n_in,
                              void* d_out, int out_size, void* d_ws, size_t ws_size,
                              hipStream_t stream)
{
    const float* X  = (const float*)d_in[0];
    const float* Wq = (const float*)d_in[1];
    const float* bq = (const float*)d_in[2];
    const float* Wk = (const float*)d_in[3];
    const float* bk = (const float*)d_in[4];
    const float* Wv = (const float*)d_in[5];
    const float* bv = (const float*)d_in[6];
    const float* Wo = (const float*)d_in[7];
    const float* bo = (const float*)d_in[8];
    const int*   ei = (const int*)d_in[9];
    float* out = (float*)d_out;

    char* ws = (char*)d_ws;
    // bitmap and QKV DISJOINT (gemm1 and csr share one fused dispatch).
    // Only alias: Xh (consumed by gemm1) <- ctx (written later by attn).
    uint32_t*       bitmap = (uint32_t*)ws;                       // [0, 8 MB)
    __half*         QKV    = (__half*)(ws + 8388608);             // 12,582,912 B
    unsigned short* Xh     = (unsigned short*)(ws + 20971520);    // 4 MB
    __half*         ctx    = (__half*)Xh;                         // alias (safe)
    unsigned short* W2Tq   = (unsigned short*)(ws + 25165824);    // 393,216 B
    unsigned short* W2To   = (unsigned short*)(ws + 25559040);    // 131,072 B
    float*          biasq  = (float*)(ws + 25690112);             // 3,072 B
    int*            nbrL   = (int*)(ws + 25693184);               // 4 MB
    int*            cntL   = (int*)(ws + 29887488);               // 32,768 B

    zero_kernel<<<2048, 256, 0, stream>>>((uint4*)bitmap);
    prep_kernel<<<4096, 256, 0, stream>>>(
        X, Wq, Wk, Wv, Wo, bq, bk, bv, ei, bitmap, Xh, W2Tq, W2To, biasq);
    gemm_csr_kernel<<<G1B + 2048, 256, 0, stream>>>(
        Xh, W2Tq, biasq, QKV, bitmap, nbrL, cntL);
    attn_kernel<<<NN / 4, 256, 0, stream>>>(QKV, nbrL, cntL, ctx);
    gemm_kernel<64, false><<<256, 256, 0, stream>>>(
        (const unsigned short*)ctx, W2To, bo, out, HID);
}

// Round 15
// 75.506 us; speedup vs baseline: 1.2538x; 1.2538x over previous
//
#include <hip/hip_runtime.h>
#include <hip/hip_fp16.h>
#include <stdint.h>

#define NN 8192          // nodes
#define HID 256          // hidden
#define NH 4             // heads
#define HD 64            // head dim
#define NE 262144        // edges
#define WPR (NN / 32)    // bitmap words per row = 256
#define CAP 128          // max neighbors per row (Binomial(262k,1/8192): max ~57)
#define NQKV 768         // fused QKV output width
#define G1B 384          // gemm1 blocks (128x128 tiles) inside fused kernel

typedef __attribute__((ext_vector_type(8))) short s16x8;      // 8 halves (4 VGPRs)
typedef __attribute__((ext_vector_type(4))) float f32x4;      // MFMA C/D frag
typedef _Float16 f16x2 __attribute__((ext_vector_type(2)));   // v_dot2 operand

__device__ __forceinline__ float fdot2(f16x2 a, f16x2 b, float c) {
#if __has_builtin(__builtin_amdgcn_fdot2)
    return __builtin_amdgcn_fdot2(a, b, c, false);
#else
    return c + (float)a.x * (float)b.x + (float)a.y * (float)b.y;
#endif
}

__device__ __forceinline__ void gload_lds16(const unsigned short* g, unsigned short* l) {
    __builtin_amdgcn_global_load_lds(
        (const __attribute__((address_space(1))) unsigned int*)g,
        (__attribute__((address_space(3))) unsigned int*)l, 16, 0, 0);
}

// ---------------------------------------------------------------------------
// Zero the bitmap: 2048 blocks x 256 thr x 16B = 8 MB
// ---------------------------------------------------------------------------
__global__ __launch_bounds__(256) void zero_kernel(uint4* __restrict__ p)
{
    p[blockIdx.x * 256 + threadIdx.x] = make_uint4(0, 0, 0, 0);
}

// ---------------------------------------------------------------------------
// Fused prep: [0,1024) edge scatter | [1024,3072) X->fp16 (4/thr)
//             [3072,4096) W^T->fp16 + qkv bias
// ---------------------------------------------------------------------------
__global__ __launch_bounds__(256) void prep_kernel(
    const float* __restrict__ X,
    const float* __restrict__ Wq, const float* __restrict__ Wk,
    const float* __restrict__ Wv, const float* __restrict__ Wo,
    const float* __restrict__ bq, const float* __restrict__ bk,
    const float* __restrict__ bv, const int* __restrict__ ei,
    uint32_t* __restrict__ bitmap, unsigned short* __restrict__ Xh,
    unsigned short* __restrict__ W2Tq, unsigned short* __restrict__ W2To,
    float* __restrict__ biasq)
{
    const int b = blockIdx.x, tid = threadIdx.x;
    if (b < 1024) {                                   // ---- edge scatter ----
        int e = b * 256 + tid;
        int r = ei[e];
        int c = ei[NE + e];
        atomicOr(&bitmap[(size_t)r * WPR + (c >> 5)], 1u << (c & 31));
    } else if (b < 3072) {                            // ---- X -> fp16 ----
        int i4 = ((b - 1024) * 256 + tid) * 4;        // covers NN*HID exactly
        float4 x = *(const float4*)(X + i4);
        __half2 h0 = __floats2half2_rn(x.x, x.y);
        __half2 h1 = __floats2half2_rn(x.z, x.w);
        uint2 w;
        w.x = *(unsigned*)&h0;
        w.y = *(unsigned*)&h1;
        *(uint2*)(Xh + i4) = w;
    } else {                                          // ---- W^T -> fp16 ----
        int lin = (b - 3072) * 256 + tid;             // 262144 = 1024*256
        int n = lin >> 8, k = lin & 255;
        const float* W; int ns; unsigned short* dst;
        if (n < NQKV) {
            W  = (n < 256) ? Wq : (n < 512) ? Wk : Wv;
            ns = n & 255;
            dst = W2Tq + (size_t)n * HID + k;
            if (k == 0) {
                const float* bsrc = (n < 256) ? bq : (n < 512) ? bk : bv;
                biasq[n] = bsrc[ns];
            }
        } else {
            W = Wo; ns = n - NQKV;
            dst = W2To + (size_t)ns * HID + k;
        }
        __half h = __float2half(W[(size_t)k * HID + ns]);
        *dst = *(unsigned short*)&h;
    }
}

// ---------------------------------------------------------------------------
// fp16 MFMA GEMM tile body (BM=128, BN template): C = A*B^T + bias, fp32 acc.
// 4 waves 2x2, each 64 x BN/2 (4 x BN/32 frags of 16x16x32 f16). K=256.
// ---------------------------------------------------------------------------
template<int BN, bool HALF_OUT>
__device__ __forceinline__ void gemm_body(
    const unsigned short* __restrict__ A, const unsigned short* __restrict__ BT,
    const float* __restrict__ bias, void* __restrict__ Cv, int N,
    int m0, int n0, unsigned short* Alds, unsigned short* Blds)
{
    constexpr int NFR = BN / 32;                    // N-frags per wave
    const int tid  = threadIdx.x;
    const int lane = tid & 63, wave = tid >> 6;
    const int wm = wave >> 1, wn = wave & 1;

    const int r0 = tid >> 2, cc0 = tid & 3;
    const int r1 = (tid + 256) >> 2, cc1 = (tid + 256) & 3;

    f32x4 acc[4][NFR];
    #pragma unroll
    for (int i = 0; i < 4; ++i)
        #pragma unroll
        for (int j = 0; j < NFR; ++j)
            acc[i][j] = (f32x4){0.f, 0.f, 0.f, 0.f};

    for (int step = 0; step < 8; ++step) {
        const int kk = step * 32;
        __syncthreads();
        gload_lds16(A + (size_t)(m0 + r0) * HID + kk + cc0 * 8, &Alds[tid * 8]);
        gload_lds16(A + (size_t)(m0 + r1) * HID + kk + cc1 * 8, &Alds[(tid + 256) * 8]);
        gload_lds16(BT + (size_t)(n0 + r0) * HID + kk + cc0 * 8, &Blds[tid * 8]);
        if constexpr (BN == 128)
            gload_lds16(BT + (size_t)(n0 + r1) * HID + kk + cc1 * 8, &Blds[(tid + 256) * 8]);
        __syncthreads();

        s16x8 af[4], bfr[NFR];
        #pragma unroll
        for (int i = 0; i < 4; ++i)
            af[i] = *(const s16x8*)&Alds[(wm * 64 + i * 16 + (lane & 15)) * 32 + (lane >> 4) * 8];
        #pragma unroll
        for (int j = 0; j < NFR; ++j)
            bfr[j] = *(const s16x8*)&Blds[(wn * (BN / 2) + j * 16 + (lane & 15)) * 32 + (lane >> 4) * 8];
        #pragma unroll
        for (int i = 0; i < 4; ++i)
            #pragma unroll
            for (int j = 0; j < NFR; ++j)
                acc[i][j] = __builtin_amdgcn_mfma_f32_16x16x32_f16(af[i], bfr[j], acc[i][j], 0, 0, 0);
    }

    // epilogue: C/D layout col=lane&15, row=(lane>>4)*4+reg
    #pragma unroll
    for (int i = 0; i < 4; ++i) {
        #pragma unroll
        for (int j = 0; j < NFR; ++j) {
            int gcol = n0 + wn * (BN / 2) + j * 16 + (lane & 15);
            float bb = bias[gcol];
            #pragma unroll
            for (int r = 0; r < 4; ++r) {
                int grow = m0 + wm * 64 + i * 16 + (lane >> 4) * 4 + r;
                float v = acc[i][j][r] + bb;
                if constexpr (HALF_OUT)
                    ((__half*)Cv)[(size_t)grow * N + gcol] = __float2half(v);
                else
                    ((float*)Cv)[(size_t)grow * N + gcol] = v;
            }
        }
    }
}

// ---------------------------------------------------------------------------
// Fused dispatch: [0, G1B) QKV GEMM (128x128 tiles, XCD swizzle) |
//                 [G1B, G1B+2048) bitmap -> capped neighbor lists (wave/row)
// ---------------------------------------------------------------------------
__global__ __launch_bounds__(256) void gemm_csr_kernel(
    const unsigned short* __restrict__ Xh, const unsigned short* __restrict__ W2Tq,
    const float* __restrict__ biasq, __half* __restrict__ QKV,
    const uint32_t* __restrict__ bitmap, int* __restrict__ nbr, int* __restrict__ cnt)
{
    __shared__ __align__(16) unsigned short Alds[128 * 32];
    __shared__ __align__(16) unsigned short Blds[128 * 32];

    if (blockIdx.x < G1B) {
        constexpr int q8 = G1B >> 3;
        const int orig = blockIdx.x;
        const int id = (orig & 7) * q8 + (orig >> 3);       // XCD-contiguous
        gemm_body<128, true>(Xh, W2Tq, biasq, QKV, NQKV,
                             (id & 63) * 128, (id >> 6) * 128, Alds, Blds);
        return;
    }
    // ---- build_csr: one wave per row ----
    const int row = (blockIdx.x - G1B) * 4 + (threadIdx.x >> 6);
    const int lane = threadIdx.x & 63;
    const uint32_t* rp = bitmap + (size_t)row * WPR + lane * 4;
    uint32_t w0 = rp[0], w1 = rp[1], w2 = rp[2], w3 = rp[3];
    int pc = __popc(w0) + __popc(w1) + __popc(w2) + __popc(w3);
    int scan = pc;
    #pragma unroll
    for (int off = 1; off < 64; off <<= 1) {
        int t = __shfl_up(scan, off);
        if (lane >= off) scan += t;
    }
    int idx = scan - pc;
    int* dst = nbr + (size_t)row * CAP;
    const int base = lane * 128;
    uint32_t ws4[4] = {w0, w1, w2, w3};
    #pragma unroll
    for (int i = 0; i < 4; ++i) {
        uint32_t w = ws4[i];
        int cb = base + i * 32;
        while (w) {
            int b = __ffs(w) - 1;
            if (idx < CAP) dst[idx] = cb + b;
            ++idx;
            w &= w - 1;
        }
    }
    if (lane == 63) cnt[row] = min(scan, CAP);
}

// ---------------------------------------------------------------------------
// Standalone GEMM (out-projection): BM=128, BN=64; 256 blocks, XCD swizzle.
// ---------------------------------------------------------------------------
template<int BN, bool HALF_OUT>
__global__ __launch_bounds__(256) void gemm_kernel(
    const unsigned short* __restrict__ A, const unsigned short* __restrict__ BT,
    const float* __restrict__ bias, void* __restrict__ Cv, int N)
{
    __shared__ __align__(16) unsigned short Alds[128 * 32];
    __shared__ __align__(16) unsigned short Blds[BN * 32];
    const int nwg = gridDim.x, orig = blockIdx.x, q8 = nwg >> 3;
    const int id = (orig & 7) * q8 + (orig >> 3);
    gemm_body<BN, HALF_OUT>(A, BT, bias, Cv, N,
                            (id & 63) * 128, (id >> 6) * BN, Alds, Blds);
}

// ---------------------------------------------------------------------------
// Sparse attention, WAVE-PER-ROW, zero LDS, zero barriers (R9/R11 optimum:
// 40 VGPR, full occupancy, TLP latency hiding, batch-8 coalesced gathers).
// Lane l owns cols 4l..4l+3 (head g=l>>4). Per batch of 8 neighbors:
// 16 coalesced 512B row loads in flight; scores via 16-lane shfl reduce;
// online softmax + PV in registers. Block = 4 independent waves = 4 rows.
// ---------------------------------------------------------------------------
__global__ __launch_bounds__(256) void attn_kernel(
    const __half* __restrict__ QKV, const int* __restrict__ nbr,
    const int* __restrict__ cntg, __half* __restrict__ ctx)
{
    const int row  = blockIdx.x * 4 + (threadIdx.x >> 6);
    const int lane = threadIdx.x & 63;
    const int cnt  = cntg[row];

    // Q slice: halves 4l..4l+3 (head g slice)
    uint2 qraw = ((const uint2*)(QKV + (size_t)row * NQKV))[lane];
    union { uint2 u2; f16x2 h[2]; } uq; uq.u2 = qraw;
    const f16x2 q2a = uq.h[0], q2b = uq.h[1];

    float m = -INFINITY, l = 0.f;
    float a0 = 0.f, a1 = 0.f, a2 = 0.f, a3 = 0.f;

    for (int j0 = 0; j0 < cnt; j0 += 64) {
        int mynb = (j0 + lane < cnt) ? nbr[(size_t)row * CAP + j0 + lane] : 0;
        const int nb = min(64, cnt - j0);
        for (int b = 0; b < nb; b += 8) {
            int idx[8];
            #pragma unroll
            for (int u = 0; u < 8; ++u) idx[u] = __shfl(mynb, b + u);
            uint2 kv[8], vv[8];
            #pragma unroll
            for (int u = 0; u < 8; ++u) {          // 16 loads in flight
                const __half* base = QKV + (size_t)idx[u] * NQKV;
                kv[u] = ((const uint2*)(base + 256))[lane];
                vv[u] = ((const uint2*)(base + 512))[lane];
            }
            float s[8];
            #pragma unroll
            for (int u = 0; u < 8; ++u) {
                union { uint2 u2; f16x2 h[2]; } uk; uk.u2 = kv[u];
                float p = fdot2(q2a, uk.h[0], 0.f);
                p = fdot2(q2b, uk.h[1], p);
                #pragma unroll
                for (int off = 1; off < 16; off <<= 1) p += __shfl_xor(p, off);
                s[u] = (b + u < nb) ? p * 0.125f : -INFINITY;
            }
            float bm = s[0];
            #pragma unroll
            for (int u = 1; u < 8; ++u) bm = fmaxf(bm, s[u]);
            float mn = fmaxf(m, bm);               // finite (>=1 valid score)
            float sc = expf(m - mn);               // first batch: exp(-inf)=0
            a0 *= sc; a1 *= sc; a2 *= sc; a3 *= sc; l *= sc;
            #pragma unroll
            for (int u = 0; u < 8; ++u) {
                float w = expf(s[u] - mn);         // masked: exp(-inf)=0
                l += w;
                union { uint2 u2; __half2 h[2]; } uv; uv.u2 = vv[u];
                float2 f0 = __half22float2(uv.h[0]);
                float2 f1 = __half22float2(uv.h[1]);
                a0 = fmaf(w, f0.x, a0); a1 = fmaf(w, f0.y, a1);
                a2 = fmaf(w, f1.x, a2); a3 = fmaf(w, f1.y, a3);
            }
            m = mn;
        }
    }

    uint2 outw = make_uint2(0u, 0u);               // cnt==0 -> zeros
    if (cnt > 0) {
        float rl = 1.f / l;
        __half2 o0 = __floats2half2_rn(a0 * rl, a1 * rl);
        __half2 o1 = __floats2half2_rn(a2 * rl, a3 * rl);
        outw.x = *(unsigned*)&o0;
        outw.y = *(unsigned*)&o1;
    }
    ((uint2*)(ctx + (size_t)row * HID))[lane] = outw;
}

// ---------------------------------------------------------------------------
extern "C" void kernel_launch(void* const* d_in, const int* in_sizes, int n_in,
                              void* d_out, int out_size, void* d_ws, size_t ws_size,
                              hipStream_t stream)
{
    const float* X  = (const float*)d_in[0];
    const float* Wq = (const float*)d_in[1];
    const float* bq = (const float*)d_in[2];
    const float* Wk = (const float*)d_in[3];
    const float* bk = (const float*)d_in[4];
    const float* Wv = (const float*)d_in[5];
    const float* bv = (const float*)d_in[6];
    const float* Wo = (const float*)d_in[7];
    const float* bo = (const float*)d_in[8];
    const int*   ei = (const int*)d_in[9];
    float* out = (float*)d_out;

    char* ws = (char*)d_ws;
    // bitmap and QKV DISJOINT (gemm1 and csr share one fused dispatch).
    // Only alias: Xh (consumed by gemm1) <- ctx (written later by attn).
    uint32_t*       bitmap = (uint32_t*)ws;                       // [0, 8 MB)
    __half*         QKV    = (__half*)(ws + 8388608);             // 12,582,912 B
    unsigned short* Xh     = (unsigned short*)(ws + 20971520);    // 4 MB
    __half*         ctx    = (__half*)Xh;                         // alias (safe)
    unsigned short* W2Tq   = (unsigned short*)(ws + 25165824);    // 393,216 B
    unsigned short* W2To   = (unsigned short*)(ws + 25559040);    // 131,072 B
    float*          biasq  = (float*)(ws + 25690112);             // 3,072 B
    int*            nbrL   = (int*)(ws + 25693184);               // 4 MB
    int*            cntL   = (int*)(ws + 29887488);               // 32,768 B

    zero_kernel<<<2048, 256, 0, stream>>>((uint4*)bitmap);
    prep_kernel<<<4096, 256, 0, stream>>>(
        X, Wq, Wk, Wv, Wo, bq, bk, bv, ei, bitmap, Xh, W2Tq, W2To, biasq);
    gemm_csr_kernel<<<G1B + 2048, 256, 0, stream>>>(
        Xh, W2Tq, biasq, QKV, bitmap, nbrL, cntL);
    attn_kernel<<<NN / 4, 256, 0, stream>>>(QKV, nbrL, cntL, ctx);
    gemm_kernel<64, false><<<256, 256, 0, stream>>>(
        (const unsigned short*)ctx, W2To, bo, out, HID);
}